// Round 4
// baseline (243.348 us; speedup 1.0000x reference)
//
#include <hip/hip_runtime.h>
#include <hip/hip_bf16.h>
#include <cstdint>
#include <cstddef>

#define BATCH 32
#define CIN   256
#define COUT  256
#define HH    56
#define WW    56
#define HP    60      // padded rows: 0..57 read; 58/59 slack (zeroed)
#define WPAD  64      // padded cols: 0,57 are conv zero-pad; 58..63 slack (zeroed)
#define KTOT  2304    // 9 * 256
#define NT    72      // K-tiles of 32

typedef __attribute__((ext_vector_type(4))) float f32x4;
typedef __attribute__((ext_vector_type(8))) short short8;

// ---------------- zero only the padding cells of xq (12.4 MB, not 63 MB) ----------------
__global__ void zeropad_kernel(unsigned short* __restrict__ xq)
{
    const int b   = blockIdx.y;
    const int idx = blockIdx.x * 256 + threadIdx.x;   // 0..22527
    const int pos = idx >> 5;
    const int ch  = (idx & 31) * 8;
    int hp, wp;
    if (pos < 256) {                     // rows {0,57,58,59} full
        int r = pos >> 6;
        hp = (r == 0) ? 0 : 56 + r;
        wp = pos & 63;
    } else {                             // rows 1..56, cols {0,57..63}
        int i2 = pos - 256;
        int c  = i2 & 7;
        hp = (i2 >> 3) + 1;
        wp = (c == 0) ? 0 : 56 + c;
    }
    short8 z = {0, 0, 0, 0, 0, 0, 0, 0};
    *reinterpret_cast<short8*>(xq + (((size_t)b * HP + hp) * WPAD + wp) * CIN + ch) = z;
}

// ---------------- BFP quantize + NCHW->padded-NHWC bf16 repack ----------------
__global__ void quant_kernel(const float* __restrict__ x, unsigned short* __restrict__ xq)
{
    const int h   = blockIdx.x;       // 0..55
    const int b   = blockIdx.y;       // 0..31
    const int tid = threadIdx.x;
    const int wv  = tid >> 6;
    const int w   = tid & 63;
    if (w >= WW) return;
    for (int cb = wv; cb < 8; cb += 4) {
        float v[32];
        float mx = 0.f;
        const float* xp = x + (((size_t)b * CIN + cb * 32) * HH + h) * WW + w;
#pragma unroll
        for (int c = 0; c < 32; ++c) {
            float t = xp[(size_t)c * HH * WW];
            v[c] = t;
            mx = fmaxf(mx, fabsf(t));
        }
        float m = fmaxf(mx, 1e-12f);
        int e;
        frexpf(m, &e);
        e -= 1;                                  // exact floor(log2(m))
        e = (e < -64) ? -64 : ((e > 63) ? 63 : e);
        float step = exp2f((float)(e - 7));
        float inv  = exp2f((float)(7 - e));
        unsigned short qb[32];
#pragma unroll
        for (int c = 0; c < 32; ++c) {
            float q = rintf(v[c] * inv);          // round-half-even, matches jnp.round
            q = fminf(fmaxf(q, -128.f), 127.f);
            float val = q * step;                 // exactly representable in bf16
            __hip_bfloat16 bv = __float2bfloat16(val);
            qb[c] = *reinterpret_cast<unsigned short*>(&bv);
        }
        unsigned short* dst = xq + (((size_t)b * HP + (h + 1)) * WPAD + (w + 1)) * CIN + cb * 32;
#pragma unroll
        for (int i = 0; i < 4; ++i)
            *reinterpret_cast<short8*>(dst + i * 8) = *reinterpret_cast<const short8*>(qb + i * 8);
    }
}

// ---------------- weight repack: OIHW fp32 -> [n][j=kh*3+kw][c] bf16 ----------------
__global__ void wrepack_kernel(const float* __restrict__ Wsrc, unsigned short* __restrict__ Wr)
{
    int idx = blockIdx.x * 256 + threadIdx.x;
    if (idx >= COUT * KTOT) return;
    int n = idx / KTOT;
    int r = idx % KTOT;
    int j = r >> 8;    // 0..8
    int c = r & 255;
    float val = Wsrc[((size_t)n * CIN + c) * 9 + j];
    __hip_bfloat16 bv = __float2bfloat16(val);
    Wr[idx] = *reinterpret_cast<unsigned short*>(&bv);
}

// ---------------- implicit-GEMM conv, 256x256 tile, BK=32, 4-buf pipelined ----------------
// LDS tile layout (fragment order): 16-row groups of 1024B; within a group,
// byte offset = kg*256 + row_in_group*16, so MFMA lane l (=kg*16+ln) reads at
// byte l*16 -> conflict-free ds_read_b128. global_load_lds writes linearly at
// lane*16, so the GLOBAL source address is pre-swizzled (row=l&15, chunk=l>>4).
//
// ONE barrier + one counted VMWAIT per K-tile (never drained in steady state):
//   WAR: stage(t+3) overwrites buf[(t-1)&3], last read in iter t-1 before that
//        iter's end barrier -> safe.
//   RAW: VMWAIT(8) at end of iter t-1 drains the 4 loads for tile t (issued in
//        iter t-3); the barrier publishes completion to all waves.
__device__ __forceinline__ void gload_lds16(const void* g, void* l)
{
    __builtin_amdgcn_global_load_lds((const __attribute__((address_space(1))) void*)g,
                                     (__attribute__((address_space(3))) void*)l, 16, 0, 0);
}

#define SCB() __builtin_amdgcn_sched_barrier(0)
#define BAR() do { SCB(); __builtin_amdgcn_s_barrier(); SCB(); } while (0)
#define VMWAIT(n) do { asm volatile("s_waitcnt vmcnt(" #n ")" ::: "memory"); } while (0)

#define K_ITER(T, STG, VM) do {                                                          \
    const int t_ = (T);                                                                  \
    const unsigned short* Ac = As + (t_ & 3) * 8192;                                     \
    const unsigned short* Bc = Bs + (t_ & 3) * 8192;                                     \
    short8 af[8], bfv[4];                                                                \
    _Pragma("unroll")                                                                    \
    for (int f = 0; f < 8; ++f) af[f]  = *(const short8*)(Ac + ardk + f * 512);          \
    _Pragma("unroll")                                                                    \
    for (int f = 0; f < 4; ++f) bfv[f] = *(const short8*)(Bc + brdk + f * 512);          \
    if (STG) { stageA(t_ + 3, 0); stageA(t_ + 3, 1);                                     \
               stageB(t_ + 3, 0); stageB(t_ + 3, 1); }                                   \
    _Pragma("unroll")                                                                    \
    for (int i = 0; i < 8; ++i)                                                          \
        _Pragma("unroll")                                                                \
        for (int j = 0; j < 4; ++j)                                                      \
            acc[i][j] = __builtin_amdgcn_mfma_f32_16x16x32_bf16(af[i], bfv[j],           \
                                                                acc[i][j], 0, 0, 0);     \
    VM;                                                                                  \
    BAR();                                                                               \
} while (0)

__global__ __launch_bounds__(512, 2) void conv_gemm_kernel(const unsigned short* __restrict__ xq,
                                                           const unsigned short* __restrict__ Wr,
                                                           float* __restrict__ out,
                                                           float* __restrict__ sums)
{
    extern __shared__ __align__(16) unsigned short lds[];
    unsigned short* As = lds;              // 4 bufs x 16 groups x 512 elem (64 KB)
    unsigned short* Bs = lds + 4 * 8192;   // 4 bufs x 16 groups x 512 elem (64 KB)

    const int bid  = blockIdx.x;                    // 0..447
    const int blk  = (bid & 7) * 56 + (bid >> 3);   // bijective XCD swizzle (448 = 8*56)
    const int b    = blk / 14;
    const int m0   = (blk % 14) * 256;
    const int tid  = threadIdx.x;
    const int wv   = tid >> 6;          // 0..7
    const int lane = tid & 63;
    const int ln   = lane & 15;
    const int kg   = lane >> 4;         // k-group 0..3
    const int wm   = wv >> 2;           // 0..1
    const int wn   = wv & 3;            // 0..3

    const unsigned short* Ab = xq + (size_t)b * (HP * WPAD * CIN);

    // fragment-order LDS read offsets (elements); frag f at +f*512
    const int ardk = wm * 4096 + lane * 8;
    const int brdk = wn * 2048 + lane * 8;
    // pre-swizzled global source offsets for linear global_load_lds dest
    const int sR = lane & 15;           // row within 16-row group
    const int sC = (lane >> 4) * 8;     // 8-elem (16B) chunk within 64B row

    auto stageA = [&](int tt, int q) {
        int j = tt >> 3, cb = tt & 7;
        int kh = j / 3, kw = j - 3 * kh;
        int aoff = (kh * WPAD + kw) * CIN + cb * 32;
        int g = 2 * wv + q;
        gload_lds16(Ab + (size_t)(m0 + g * 16 + sR) * CIN + aoff + sC,
                    (void*)(As + (tt & 3) * 8192 + g * 512));
    };
    auto stageB = [&](int tt, int q) {
        int j = tt >> 3, cb = tt & 7;
        int g = 2 * wv + q;
        gload_lds16(Wr + (size_t)(g * 16 + sR) * KTOT + j * 256 + cb * 32 + sC,
                    (void*)(Bs + (tt & 3) * 8192 + g * 512));
    };

    f32x4 acc[8][4];
#pragma unroll
    for (int i = 0; i < 8; ++i)
#pragma unroll
        for (int jn = 0; jn < 4; ++jn) acc[i][jn] = (f32x4){0.f, 0.f, 0.f, 0.f};

    // prologue: stage tiles 0,1,2 (12 loads/thread); wait for tile 0 only
    stageA(0, 0); stageA(0, 1); stageB(0, 0); stageB(0, 1);
    stageA(1, 0); stageA(1, 1); stageB(1, 0); stageB(1, 1);
    stageA(2, 0); stageA(2, 1); stageB(2, 0); stageB(2, 1);
    VMWAIT(8);
    BAR();

    for (int t = 0; t < NT - 3; ++t) { K_ITER(t, true, VMWAIT(8)); }
    K_ITER(NT - 3, false, VMWAIT(4));
    K_ITER(NT - 2, false, VMWAIT(0));
    K_ITER(NT - 1, false, (void)0);

    // epilogue: C/D layout col=lane&15 (n), row=(lane>>4)*4+reg (m).
    // r=0..3 are consecutive w -> f32x4 stores; w<56 mask == !(i%4==3 && kg>=2).
    // Fused BN stats: per-thread (s,s2) per n, shfl-reduce over kg, atomicAdd.
#pragma unroll
    for (int jn = 0; jn < 4; ++jn) {
        const int n = wn * 64 + jn * 16 + ln;
        float s = 0.f, s2 = 0.f;
#pragma unroll
        for (int i = 0; i < 8; ++i) {
            if ((i & 3) == 3 && kg >= 2) continue;   // w = 56..63: padding lanes
            const int mm = m0 + wm * 128 + i * 16 + kg * 4;
            const int h = mm >> 6, w = mm & 63;
            f32x4 v = acc[i][jn];
            s  += v[0] + v[1] + v[2] + v[3];
            s2 += v[0] * v[0] + v[1] * v[1] + v[2] * v[2] + v[3] * v[3];
            *reinterpret_cast<f32x4*>(&out[(((size_t)b * COUT + n) * HH + h) * WW + w]) = v;
        }
        s  += __shfl_xor(s, 16);  s  += __shfl_xor(s, 32);
        s2 += __shfl_xor(s2, 16); s2 += __shfl_xor(s2, 32);
        if (kg == 0) {
            atomicAdd(&sums[n], s);
            atomicAdd(&sums[COUT + n], s2);
        }
    }
}

// ---------------- BN normalize + affine + ReLU (in place, f32x4) ----------------
__global__ void bn_apply_kernel(float* __restrict__ y, const float* __restrict__ sums,
                                const float* __restrict__ gamma, const float* __restrict__ beta)
{
    const int o = blockIdx.x, b = blockIdx.y;
    const float N = (float)(BATCH * HH * WW);
    const float mean = sums[o] / N;
    const float var  = sums[COUT + o] / N - mean * mean;
    const float inv  = 1.f / sqrtf(var + 1e-5f);
    const float a  = gamma[o] * inv;
    const float bb = beta[o] - mean * a;
    float* p = y + ((size_t)b * COUT + o) * (HH * WW);
    // 3136 floats = 784 f32x4 chunks
    for (int i = threadIdx.x; i < 784; i += 256) {
        f32x4 v = *reinterpret_cast<const f32x4*>(p + i * 4);
#pragma unroll
        for (int r = 0; r < 4; ++r) v[r] = fmaxf(v[r] * a + bb, 0.f);
        *reinterpret_cast<f32x4*>(p + i * 4) = v;
    }
}

extern "C" void kernel_launch(void* const* d_in, const int* in_sizes, int n_in,
                              void* d_out, int out_size, void* d_ws, size_t ws_size,
                              hipStream_t stream)
{
    const float* x     = (const float*)d_in[0];
    const float* Wsrc  = (const float*)d_in[1];
    const float* gamma = (const float*)d_in[2];
    const float* beta  = (const float*)d_in[3];
    float* out = (float*)d_out;

    char* ws = (char*)d_ws;
    const size_t XQ_BYTES = (size_t)BATCH * HP * WPAD * CIN * 2;  // 62,914,560
    const size_t WR_BYTES = (size_t)COUT * KTOT * 2;              //  1,179,648
    unsigned short* xq = (unsigned short*)ws;
    unsigned short* wr = (unsigned short*)(ws + XQ_BYTES);
    float* sums = (float*)(ws + XQ_BYTES + WR_BYTES);

    hipMemsetAsync(sums, 0, 2 * COUT * sizeof(float), stream);

    zeropad_kernel<<<dim3(88, BATCH), 256, 0, stream>>>(xq);
    quant_kernel<<<dim3(HH, BATCH), 256, 0, stream>>>(x, xq);
    wrepack_kernel<<<(COUT * KTOT + 255) / 256, 256, 0, stream>>>(Wsrc, wr);

    hipFuncSetAttribute(reinterpret_cast<const void*>(&conv_gemm_kernel),
                        hipFuncAttributeMaxDynamicSharedMemorySize, 131072);
    conv_gemm_kernel<<<448, 512, 131072, stream>>>(xq, wr, out, sums);

    bn_apply_kernel<<<dim3(COUT, BATCH), 256, 0, stream>>>(out, sums, gamma, beta);
}